// Round 7
// baseline (189.555 us; speedup 1.0000x reference)
//
#include <hip/hip_runtime.h>

#define B_    16
#define CIN   32
#define H_    128
#define W_    128
#define COUT  32
#define OH_   256
#define OW_   256

typedef __attribute__((ext_vector_type(8))) short bf8_t;   // 8 bf16 (4 VGPRs)
typedef __attribute__((ext_vector_type(4))) float f32x4;

__device__ inline unsigned int f2bf(float f) {
    unsigned int u = __float_as_uint(f);
    return (u + 0x7fffu + ((u >> 16) & 1u)) >> 16;   // RNE
}

// ---- weights f32 [ci][co][kh][kw] -> bf16 wt[khkw][co][ci] (32 KB, L2-hot) ----
__global__ __launch_bounds__(256)
void prep_w(const float* __restrict__ wgt, unsigned short* __restrict__ wt) {
    int e = blockIdx.x * 256 + threadIdx.x;          // 16384 total
    int khkw = e >> 10, co = (e >> 5) & 31, ci = e & 31;
    wt[e] = (unsigned short)f2bf(wgt[(ci * COUT + co) * 16 + khkw]);
}

// issue 8 ci-plane loads for staging cell `cell` of combo c (hr = c>>2, gp = c&3)
__device__ __forceinline__ void issue8(const float* __restrict__ x, int n, int tt0,
                                       int u0, int c, int cell, float v[8]) {
    const int hr = c >> 2, gp = c & 3;
    const int ih = tt0 - 1 + hr;
    const int iw = u0 - 1 + cell;
    const bool inb = ((unsigned)ih < H_) && ((unsigned)iw < W_);
    const float* xq = x + (((long)(n * CIN + gp * 8) * H_ + ih) * W_ + iw);
#pragma unroll
    for (int k = 0; k < 8; ++k)
        v[k] = inb ? xq[(long)k * (H_ * W_)] : 0.0f;
}

// pack 8 f32 -> 8 bf16, ds_write_b128 into slot-swizzled LDS cell
__device__ __forceinline__ void pack_write(unsigned short* __restrict__ xsb, int u0,
                                           int c, int cell, const float v[8]) {
    const int hr = c >> 2, gp = c & 3;
    const int iw = u0 - 1 + cell;
    uint4 pk;
    pk.x = f2bf(v[0]) | (f2bf(v[1]) << 16);
    pk.y = f2bf(v[2]) | (f2bf(v[3]) << 16);
    pk.z = f2bf(v[4]) | (f2bf(v[5]) << 16);
    pk.w = f2bf(v[6]) | (f2bf(v[7]) << 16);
    const int slot = gp ^ ((iw >> 1) & 3);
    *(uint4*)(xsb + (hr * 66 + cell) * 32 + slot * 8) = pk;
}

// one parity-row pass over a staged 4-t-row tile (8 MFMAs x 4 strips + stores)
__device__ __forceinline__ void compute_po(const unsigned short* __restrict__ xsb,
                                           const unsigned short* __restrict__ wp,
                                           const float bias4[4], int n, int tt0,
                                           int trow, int u0, int ch, int g, int li,
                                           int po, float* __restrict__ y) {
    const int kh0 = po ? 0 : 1, dh0 = po ? 2 : 1;   // tap row A
    const int kh1 = po ? 2 : 3, dh1 = po ? 1 : 0;   // tap row B

    bf8_t wfA[4], wfB[4];
#pragma unroll
    for (int kw = 0; kw < 4; ++kw) {
        wfA[kw] = *(const bf8_t*)(wp + (kh0 * 4 + kw) * 1024);
        wfB[kw] = *(const bf8_t*)(wp + (kh1 * 4 + kw) * 1024);
    }

    const int t = tt0 + trow;
#pragma unroll
    for (int st = 0; st < 4; ++st) {
        const int us = u0 + st * 16;

        bf8_t xfA[3], xfB[3];
#pragma unroll
        for (int dw = 0; dw < 3; ++dw) {
            const int wg   = us + li + dw - 1;
            const int wl   = wg - (u0 - 1);
            const int slot = g ^ ((wg >> 1) & 3);
            xfA[dw] = *(const bf8_t*)(xsb + ((trow + dh0) * 66 + wl) * 32 + slot * 8);
            xfB[dw] = *(const bf8_t*)(xsb + ((trow + dh1) * 66 + wl) * 32 + slot * 8);
        }

        f32x4 acc[2];
#pragma unroll
        for (int qo = 0; qo < 2; ++qo)
            acc[qo] = (f32x4){bias4[0], bias4[1], bias4[2], bias4[3]};

#pragma unroll
        for (int qo = 0; qo < 2; ++qo) {
            const int dw0 = qo ? 2 : 1, kw0 = qo ? 0 : 1;
            const int dw1 = qo ? 1 : 0, kw1 = qo ? 2 : 3;
            acc[qo] = __builtin_amdgcn_mfma_f32_16x16x32_bf16(
                wfA[kw0], xfA[dw0], acc[qo], 0, 0, 0);
            acc[qo] = __builtin_amdgcn_mfma_f32_16x16x32_bf16(
                wfA[kw1], xfA[dw1], acc[qo], 0, 0, 0);
            acc[qo] = __builtin_amdgcn_mfma_f32_16x16x32_bf16(
                wfB[kw0], xfB[dw0], acc[qo], 0, 0, 0);
            acc[qo] = __builtin_amdgcn_mfma_f32_16x16x32_bf16(
                wfB[kw1], xfB[dw1], acc[qo], 0, 0, 0);
        }

        const int oh = 2 * t + po;
#pragma unroll
        for (int r = 0; r < 4; ++r) {
            const int co = ch * 16 + g * 4 + r;
            float* yp = y + (((long)(n * COUT + co) * OH_ + oh) * OW_) + 2 * (us + li);
            *(float2*)yp = make_float2(acc[0][r], acc[1][r]);
        }
    }
}

// ---- fused, double-buffered 2-tile walk: grid 512 = 2 blocks/CU, one shot ----
// Block: (n, u-strip of 64, 8 t-rows = tiles at tb and tb+4), 512 thr / 8 waves.
// T14 async-STAGE: tile-B loads issued before compute-A, packed+written after.
__global__ __launch_bounds__(512, 4)
void convt_fused(const float* __restrict__ x,
                 const unsigned short* __restrict__ wt,
                 const float* __restrict__ bias,
                 float* __restrict__ y) {
    __shared__ unsigned short xs[2][6 * 66 * 32];   // 2 x 25344 B

    const int tid  = threadIdx.x;
    const int lane = tid & 63;
    const int wv   = tid >> 6;
    const int n    = blockIdx.z;
    const int tb   = blockIdx.y * 8;   // tile A: tb, tile B: tb+4
    const int u0   = blockIdx.x * 64;

    // ---- stage tile A into xs[0] (cold, once per block, all blocks parallel)
#pragma unroll
    for (int j = 0; j < 3; ++j) {
        float v[8];
        issue8(x, n, tb, u0, wv + j * 8, lane, v);
        pack_write(xs[0], u0, wv + j * 8, lane, v);
    }
    if (tid < 48) {
        float v[8];
        issue8(x, n, tb, u0, tid >> 1, 64 + (tid & 1), v);
        pack_write(xs[0], u0, tid >> 1, 64 + (tid & 1), v);
    }

    const int ch   = wv & 1;      // co half
    const int trow = wv >> 1;     // 0..3
    const int g    = lane >> 4;   // k-chunk (ci group)
    const int li   = lane & 15;   // A: co row / B: pixel col

    float bias4[4];
#pragma unroll
    for (int r = 0; r < 4; ++r) bias4[r] = bias[ch * 16 + g * 4 + r];
    const unsigned short* wp = wt + (ch * 16 + li) * 32 + g * 8;

    __syncthreads();

    // ---- prefetch chunk A for tile B (issue-early; pack/write late)
    float vA0[8], vA1[8];
    issue8(x, n, tb + 4, u0, wv,     lane, vA0);
    issue8(x, n, tb + 4, u0, wv + 8, lane, vA1);

    compute_po(xs[0], wp, bias4, n, tb, trow, u0, ch, g, li, 0, y);

    pack_write(xs[1], u0, wv,     lane, vA0);
    pack_write(xs[1], u0, wv + 8, lane, vA1);
    float vB0[8], vT[8];
    issue8(x, n, tb + 4, u0, wv + 16, lane, vB0);
    const bool hasT = (tid < 48);
    if (hasT) issue8(x, n, tb + 4, u0, tid >> 1, 64 + (tid & 1), vT);

    compute_po(xs[0], wp, bias4, n, tb, trow, u0, ch, g, li, 1, y);

    pack_write(xs[1], u0, wv + 16, lane, vB0);
    if (hasT) pack_write(xs[1], u0, tid >> 1, 64 + (tid & 1), vT);

    __syncthreads();

    // ---- tile B
    compute_po(xs[1], wp, bias4, n, tb + 4, trow, u0, ch, g, li, 0, y);
    compute_po(xs[1], wp, bias4, n, tb + 4, trow, u0, ch, g, li, 1, y);
}

extern "C" void kernel_launch(void* const* d_in, const int* in_sizes, int n_in,
                              void* d_out, int out_size, void* d_ws, size_t ws_size,
                              hipStream_t stream) {
    const float* x = (const float*)d_in[0];
    const float* w = (const float*)d_in[1];
    const float* b = (const float*)d_in[2];
    float* y = (float*)d_out;

    unsigned short* wt = (unsigned short*)d_ws;   // 32 KB

    prep_w<<<64, 256, 0, stream>>>(w, wt);
    convt_fused<<<dim3(2, 16, B_), 512, 0, stream>>>(x, wt, b, y);
}